// Round 1
// baseline (1373.291 us; speedup 1.0000x reference)
//
#include <hip/hip_runtime.h>
#include <hip/hip_bf16.h>

// Problem constants (fixed by reference)
#define HD 256
#define NG 64
#define NNODES 10000
#define NEDGES 160000
#define MBLK 256
#define NTHREADS 512

typedef __attribute__((ext_vector_type(8))) short short8;
typedef __attribute__((ext_vector_type(4))) float f32x4;

__device__ __forceinline__ unsigned short f2bf(float f) {
  unsigned int u = __float_as_uint(f);
  u += 0x7FFFu + ((u >> 16) & 1u);   // RNE
  return (unsigned short)(u >> 16);
}
__device__ __forceinline__ float silu_f(float x) {
  return x / (1.0f + __expf(-x));
}

// ---------------------------------------------------------------------------
// Prep: W1/W2/W3 (f32, [cin][cout]) -> Wt bf16 transposed [mat][cout][cin]
// ---------------------------------------------------------------------------
__global__ void prep_weights(const float* __restrict__ W1, const float* __restrict__ W2,
                             const float* __restrict__ W3, unsigned short* __restrict__ Wt) {
  int idx = blockIdx.x * blockDim.x + threadIdx.x;   // 3*65536 threads exactly
  int mat = idx >> 16;
  int rem = idx & 65535;
  int n = rem >> 8, k = rem & 255;                   // n=cout, k=cin
  const float* W = (mat == 0) ? W1 : (mat == 1) ? W2 : W3;
  Wt[idx] = f2bf(W[k * 256 + n]);
}

// ---------------------------------------------------------------------------
// Fused mlp1 (3x GEMM 256x256 + SiLU) + segment-sum pooling via one-hot GEMM.
// Grid: 255 blocks = 3 heads x (5 node-blocks + 80 edge-blocks), 512 threads.
// LDS: stage [256][256] bf16 (128KB, swizzled) + S^T [64][256] bf16 (32KB).
// ---------------------------------------------------------------------------
__global__ __launch_bounds__(NTHREADS, 2)
void fused_mlp1_pool(
    const float* __restrict__ nf0, const float* __restrict__ ef0,
    const int* __restrict__ ei0, const int* __restrict__ bt0,
    const float* __restrict__ nf1, const float* __restrict__ ef1,
    const int* __restrict__ ei1, const int* __restrict__ bt1,
    const float* __restrict__ nf2, const float* __restrict__ ef2,
    const int* __restrict__ ei2, const int* __restrict__ bt2,
    const float* __restrict__ b1, const float* __restrict__ b2,
    const float* __restrict__ b3,
    const unsigned short* __restrict__ Wt, float* __restrict__ pooled) {

  extern __shared__ char lds_raw[];
  char* stageB = lds_raw;            // 131072 B
  char* SB = lds_raw + 131072;       // 32768 B

  const int tid = threadIdx.x;
  const int wid = tid >> 6, lane = tid & 63;
  const int l15 = lane & 15, lhi = lane >> 4;
  const int wr = wid >> 2, wc = wid & 3;   // 2 row-halves x 4 col-quarters

  const int bid = blockIdx.x;              // 0..254
  const int head = bid / 85;
  const int r85 = bid % 85;
  const int isEdge = (r85 >= 5) ? 1 : 0;
  const int lb = isEdge ? (r85 - 5) : r85;
  const int Bs = isEdge ? 80 : 5;
  const int rows = isEdge ? NEDGES : NNODES;
  const int ntiles = (rows + MBLK - 1) / MBLK;   // 625 or 40

  const float* X; const int* bt; const int* recv;
  if (head == 0)      { X = isEdge ? ef0 : nf0; bt = bt0; recv = ei0 + NEDGES; }
  else if (head == 1) { X = isEdge ? ef1 : nf1; bt = bt1; recv = ei1 + NEDGES; }
  else                { X = isEdge ? ef2 : nf2; bt = bt2; recv = ei2 + NEDGES; }
  float* pool = pooled + (head * 2 + isEdge) * (NG * HD);

  // Pooled accumulator in registers: P[64 g][32 cols per wave], persists all tiles.
  f32x4 pacc[4][2];
  #pragma unroll
  for (int mt = 0; mt < 4; mt++)
    #pragma unroll
    for (int n = 0; n < 2; n++) pacc[mt][n] = (f32x4){0.f, 0.f, 0.f, 0.f};

  // zero S once (re-zeroed at end of each tile, after P-GEMM reads)
  #pragma unroll
  for (int i = 0; i < 4; i++) ((int4*)SB)[tid + NTHREADS * i] = make_int4(0, 0, 0, 0);
  __syncthreads();

  for (int t = lb; t < ntiles; t += Bs) {
    const int rbase = t * MBLK;

    // ---- stage X (f32 -> bf16, swizzled) + scatter one-hot S ----
    #pragma unroll 4
    for (int i = 0; i < 32; i++) {
      int rr = wid + i * 8;
      int gr = rbase + rr; if (gr > rows - 1) gr = rows - 1;   // clamp pads
      f32x4 v = *(const f32x4*)(X + (long)gr * HD + lane * 4);
      unsigned long long pk =
          (unsigned long long)f2bf(v.x) |
          ((unsigned long long)f2bf(v.y) << 16) |
          ((unsigned long long)f2bf(v.z) << 32) |
          ((unsigned long long)f2bf(v.w) << 48);
      int byte = (rr * 512 + lane * 8) ^ ((rr & 7) << 4);
      *(unsigned long long*)(stageB + byte) = pk;
    }
    if (tid < MBLK) {
      int gr = rbase + tid;
      if (gr < rows) {
        int g = isEdge ? bt[recv[gr]] : bt[gr];
        int byte = (g * 512 + tid * 2) ^ ((g & 7) << 4);
        *(unsigned short*)(SB + byte) = 0x3F80;   // bf16 1.0
      }
    }
    __syncthreads();

    // ---- 3 chained GEMMs: h = silu(h @ W + b), in-place in stage LDS ----
    #pragma unroll 1
    for (int layer = 0; layer < 3; layer++) {
      const unsigned short* Wl = Wt + layer * 65536;
      const float* bias = (layer == 0) ? b1 : (layer == 1) ? b2 : b3;

      f32x4 acc[8][4];   // wave tile: 128 rows x 64 cols
      #pragma unroll
      for (int n = 0; n < 4; n++) {
        float bv = bias[wc * 64 + n * 16 + l15];
        #pragma unroll
        for (int m = 0; m < 8; m++) acc[m][n] = (f32x4){bv, bv, bv, bv};
      }

      #pragma unroll 2
      for (int k = 0; k < 8; k++) {
        short8 bfrag[4];
        #pragma unroll
        for (int n = 0; n < 4; n++) {
          int cout = wc * 64 + n * 16 + l15;
          bfrag[n] = *(const short8*)(Wl + cout * 256 + k * 32 + lhi * 8);
        }
        #pragma unroll
        for (int m = 0; m < 8; m++) {
          int row = wr * 128 + m * 16 + l15;
          int byte = (row * 512 + k * 64 + lhi * 16) ^ ((row & 7) << 4);
          short8 a = *(const short8*)(stageB + byte);
          #pragma unroll
          for (int n = 0; n < 4; n++)
            acc[m][n] = __builtin_amdgcn_mfma_f32_16x16x32_bf16(a, bfrag[n], acc[m][n], 0, 0, 0);
        }
      }
      __syncthreads();   // all stage reads done before overwrite

      if (layer < 2) {
        // silu + write back row-major (next GEMM's A)
        #pragma unroll
        for (int m = 0; m < 8; m++) {
          #pragma unroll
          for (int n = 0; n < 4; n++) {
            int col = wc * 64 + n * 16 + l15;
            #pragma unroll
            for (int j = 0; j < 4; j++) {
              int row = wr * 128 + m * 16 + lhi * 4 + j;
              unsigned short hv = f2bf(silu_f(acc[m][n][j]));
              int byte = (row * 512 + col * 2) ^ ((row & 7) << 4);
              *(unsigned short*)(stageB + byte) = hv;
            }
          }
        }
      } else {
        // last layer: write h3 TRANSPOSED [col][row] (packed b64) for P-GEMM B-frags
        #pragma unroll
        for (int m = 0; m < 8; m++) {
          #pragma unroll
          for (int n = 0; n < 4; n++) {
            int col = wc * 64 + n * 16 + l15;
            int row0 = wr * 128 + m * 16 + lhi * 4;
            unsigned long long pk =
                (unsigned long long)f2bf(silu_f(acc[m][n][0])) |
                ((unsigned long long)f2bf(silu_f(acc[m][n][1])) << 16) |
                ((unsigned long long)f2bf(silu_f(acc[m][n][2])) << 32) |
                ((unsigned long long)f2bf(silu_f(acc[m][n][3])) << 48);
            int byte = (col * 512 + row0 * 2) ^ ((col & 7) << 4);
            *(unsigned long long*)(stageB + byte) = pk;
          }
        }
      }
      __syncthreads();
    }

    // ---- P-GEMM: pacc += S^T(64x256) @ h3(256x256), wave owns cols [wid*32, +32) ----
    #pragma unroll 2
    for (int k = 0; k < 8; k++) {
      short8 bh[2];
      #pragma unroll
      for (int n = 0; n < 2; n++) {
        int col = wid * 32 + n * 16 + l15;
        int byte = (col * 512 + k * 64 + lhi * 16) ^ ((col & 7) << 4);
        bh[n] = *(const short8*)(stageB + byte);
      }
      #pragma unroll
      for (int mt = 0; mt < 4; mt++) {
        int g = mt * 16 + l15;
        int byte = (g * 512 + k * 64 + lhi * 16) ^ ((g & 7) << 4);
        short8 aS = *(const short8*)(SB + byte);
        #pragma unroll
        for (int n = 0; n < 2; n++)
          pacc[mt][n] = __builtin_amdgcn_mfma_f32_16x16x32_bf16(aS, bh[n], pacc[mt][n], 0, 0, 0);
      }
    }
    __syncthreads();       // P-GEMM reads of S done everywhere
    #pragma unroll
    for (int i = 0; i < 4; i++) ((int4*)SB)[tid + NTHREADS * i] = make_int4(0, 0, 0, 0);
    __syncthreads();       // S clean + stage free for next tile
  }

  // ---- flush pooled partials (once per block) ----
  #pragma unroll
  for (int mt = 0; mt < 4; mt++) {
    #pragma unroll
    for (int n = 0; n < 2; n++) {
      int col = wid * 32 + n * 16 + l15;
      #pragma unroll
      for (int j = 0; j < 4; j++) {
        int g = mt * 16 + lhi * 4 + j;
        unsafeAtomicAdd(&pool[g * HD + col], pacc[mt][n][j]);
      }
    }
  }
}

// ---------------------------------------------------------------------------
// mlp2 on pooled (64 graphs) + combine lp - pk - lg. One block per graph.
// ---------------------------------------------------------------------------
__global__ void mlp2_kernel(const float* __restrict__ pooled,
                            const float* __restrict__ V1, const float* __restrict__ c1,
                            const float* __restrict__ V2, const float* __restrict__ c2,
                            const float* __restrict__ V3, const float* __restrict__ c3,
                            float* __restrict__ out) {
  __shared__ float x[512];
  __shared__ float hb[256];
  __shared__ float wsum[4];
  const int g = blockIdx.x, t = threadIdx.x;   // 256 threads
  float total = 0.0f;

  #pragma unroll 1
  for (int head = 0; head < 3; head++) {
    x[t]       = pooled[(head * 2 + 0) * NG * HD + g * HD + t];
    x[t + 256] = pooled[(head * 2 + 1) * NG * HD + g * HD + t];
    __syncthreads();

    float a = c1[t];
    #pragma unroll 8
    for (int k = 0; k < 512; k++) a += x[k] * V1[k * HD + t];
    a = silu_f(a);
    hb[t] = a;
    __syncthreads();

    float b = c2[t];
    #pragma unroll 8
    for (int k = 0; k < 256; k++) b += hb[k] * V2[k * HD + t];
    b = silu_f(b);

    float p = b * V3[t];
    #pragma unroll
    for (int off = 32; off > 0; off >>= 1) p += __shfl_down(p, off, 64);
    if ((t & 63) == 0) wsum[t >> 6] = p;
    __syncthreads();
    if (t == 0) {
      float s = wsum[0] + wsum[1] + wsum[2] + wsum[3] + c3[0];
      total += (head == 0) ? s : -s;
    }
    __syncthreads();   // protect x/hb/wsum reuse
  }
  if (t == 0) out[g] = total;
}

// ---------------------------------------------------------------------------
extern "C" void kernel_launch(void* const* d_in, const int* in_sizes, int n_in,
                              void* d_out, int out_size, void* d_ws, size_t ws_size,
                              hipStream_t stream) {
  const float* nf0 = (const float*)d_in[0];
  const float* ef0 = (const float*)d_in[1];
  const int*   ei0 = (const int*)d_in[2];
  const int*   bt0 = (const int*)d_in[3];
  const float* nf1 = (const float*)d_in[4];
  const float* ef1 = (const float*)d_in[5];
  const int*   ei1 = (const int*)d_in[6];
  const int*   bt1 = (const int*)d_in[7];
  const float* nf2 = (const float*)d_in[8];
  const float* ef2 = (const float*)d_in[9];
  const int*   ei2 = (const int*)d_in[10];
  const int*   bt2 = (const int*)d_in[11];
  const float* W1 = (const float*)d_in[12]; const float* b1 = (const float*)d_in[13];
  const float* W2 = (const float*)d_in[14]; const float* b2 = (const float*)d_in[15];
  const float* W3 = (const float*)d_in[16]; const float* b3 = (const float*)d_in[17];
  const float* V1 = (const float*)d_in[18]; const float* c1 = (const float*)d_in[19];
  const float* V2 = (const float*)d_in[20]; const float* c2 = (const float*)d_in[21];
  const float* V3 = (const float*)d_in[22]; const float* c3 = (const float*)d_in[23];

  float* pooled = (float*)d_ws;                                   // 6*64*256 f32 = 384KB
  unsigned short* Wt = (unsigned short*)((char*)d_ws + 393216);   // 3*65536 bf16 = 384KB

  hipMemsetAsync(pooled, 0, 393216, stream);
  prep_weights<<<768, 256, 0, stream>>>(W1, W2, W3, Wt);

  hipFuncSetAttribute((const void*)fused_mlp1_pool,
                      hipFuncAttributeMaxDynamicSharedMemorySize, 163840);
  fused_mlp1_pool<<<255, NTHREADS, 163840, stream>>>(
      nf0, ef0, ei0, bt0, nf1, ef1, ei1, bt1, nf2, ef2, ei2, bt2,
      b1, b2, b3, Wt, pooled);

  mlp2_kernel<<<64, 256, 0, stream>>>(pooled, V1, c1, V2, c2, V3, c3, (float*)d_out);
}